// Round 7
// baseline (221.690 us; speedup 1.0000x reference)
//
#include <hip/hip_runtime.h>
#include <math.h>

#define BB 4
#define TT 4096
#define CC 768
#define HH 64
#define NN 192   // 3*HH output cols of fused QKV GEMM
#define LDP 72   // padded LDS row stride in bf16 elems (attn_full fallback)
#define GR 32    // rows per qkv_gemm block (R12 proven)
#define XSTR 776 // qkv A-tile LDS row stride (97*8 elems, 16B-aligned)
#define SC2 0.180336880f   // 0.125 * log2(e): QK scale folded with exp->exp2

typedef __bf16 bf16x8 __attribute__((ext_vector_type(8)));
typedef float floatx4 __attribute__((ext_vector_type(4)));
typedef float floatx16 __attribute__((ext_vector_type(16)));
typedef unsigned short u16x8 __attribute__((ext_vector_type(8)));

__device__ inline unsigned short f2bf(float f) {
    union { __bf16 b; unsigned short u; } v;
    v.b = (__bf16)f;                      // hw cvt (RTNE) on gfx950
    return v.u;
}
__device__ inline float bf2f(unsigned short u) {
    union { unsigned int u; float f; } v;
    v.u = (unsigned int)u << 16;
    return v.f;
}
__device__ inline unsigned cvtpk(float lo, float hi) {
    unsigned d;
    asm("v_cvt_pk_bf16_f32 %0, %1, %2" : "=v"(d) : "v"(lo), "v"(hi));
    return d;
}

// ---------------- Kernel 0: W prep — fragment-order B (+ counter zeroing) ---
__global__ __launch_bounds__(256) void wprep(const float* __restrict__ Wq,
                                             const float* __restrict__ Wk,
                                             const float* __restrict__ Wv,
                                             unsigned short* __restrict__ wtf,
                                             int* __restrict__ cnt) {
    const int idx = blockIdx.x * 256 + threadIdx.x;
    if (idx < 256) cnt[idx] = 0;            // split-K completion counters
    if (idx >= NN * CC) return;
    const int j = idx & 7;
    const int lane = (idx >> 3) & 63;
    const int rest = idx >> 9;              // 0..287
    const int kg = rest % 24;
    const int n_tile = rest / 24;
    const int c = kg * 32 + (lane >> 4) * 8 + j;
    const int n = n_tile * 16 + (lane & 15);
    const float* W = (n < 64) ? Wq : (n < 128) ? Wk : Wv;
    wtf[idx] = f2bf(W[c * HH + (n & 63)]);
}

// ---------------- Kernel 1: fused QKV projection MFMA GEMM (R12/GR32) -------
__global__ __launch_bounds__(256) void qkv_gemm(const float* __restrict__ x,
                                                const unsigned short* __restrict__ wtf,
                                                unsigned short* __restrict__ qb,
                                                unsigned short* __restrict__ kb,
                                                unsigned short* __restrict__ vbt) {
    __shared__ unsigned short As[GR * XSTR];  // 48.5 KB

    const int tid = threadIdx.x;
    const int w = tid >> 6, lane = tid & 63;
    const int l15 = lane & 15, quad = lane >> 4;
    const int m0 = blockIdx.x * GR;
    const int n0 = w * 48;
    const int nt0 = w * 3;

    const float* xbase = x + (size_t)m0 * CC;
#pragma unroll
    for (int e = 0; e < 12; ++e) {
        const int c = tid + 256 * e;          // 0..3071
        const int r = c / 96, off = (c - r * 96) * 8;
        const float4 v0 = *(const float4*)(xbase + (size_t)c * 8);
        const float4 v1 = *(const float4*)(xbase + (size_t)c * 8 + 4);
        u16x8 pk;
        pk[0] = f2bf(v0.x); pk[1] = f2bf(v0.y); pk[2] = f2bf(v0.z); pk[3] = f2bf(v0.w);
        pk[4] = f2bf(v1.x); pk[5] = f2bf(v1.y); pk[6] = f2bf(v1.z); pk[7] = f2bf(v1.w);
        *(u16x8*)(As + r * XSTR + off) = pk;
    }
    __syncthreads();                          // the ONLY barrier

    floatx4 acc[2][3] = {};
#pragma unroll 4
    for (int step = 0; step < 12; ++step) {
        bf16x8 a0[2], a1[2];
#pragma unroll
        for (int rg = 0; rg < 2; ++rg) {
            const unsigned short* ap = As + (16 * rg + l15) * XSTR + step * 64 + quad * 8;
            a0[rg] = *(const bf16x8*)(ap);
            a1[rg] = *(const bf16x8*)(ap + 32);
        }
#pragma unroll
        for (int j = 0; j < 3; ++j) {
            const unsigned short* bp =
                wtf + ((size_t)((nt0 + j) * 24 + 2 * step) * 64 + lane) * 8;
            const bf16x8 b0 = *(const bf16x8*)(bp);
            const bf16x8 b1 = *(const bf16x8*)(bp + 512);
#pragma unroll
            for (int rg = 0; rg < 2; ++rg) {
                acc[rg][j] = __builtin_amdgcn_mfma_f32_16x16x32_bf16(a0[rg], b0, acc[rg][j], 0, 0, 0);
                acc[rg][j] = __builtin_amdgcn_mfma_f32_16x16x32_bf16(a1[rg], b1, acc[rg][j], 0, 0, 0);
            }
        }
    }

    const int b = m0 >> 12;
#pragma unroll
    for (int j = 0; j < 3; ++j) {
        const int n = n0 + j * 16 + l15;
        const int mid = n >> 6;                  // 0=Q,1=K,2=V
        const int h = n & 63;
#pragma unroll
        for (int rg = 0; rg < 2; ++rg) {
            const int tloc = (m0 & (TT - 1)) + 16 * rg + quad * 4;
            if (mid == 2) {
                ushort4 pk;
                pk.x = f2bf(acc[rg][j][0]); pk.y = f2bf(acc[rg][j][1]);
                pk.z = f2bf(acc[rg][j][2]); pk.w = f2bf(acc[rg][j][3]);
                *(ushort4*)(vbt + ((size_t)b * HH + h) * TT + tloc) = pk;
            } else {
                unsigned short* dst = (mid == 0) ? qb : kb;
#pragma unroll
                for (int r = 0; r < 4; ++r)
                    dst[(size_t)(m0 + 16 * rg + quad * 4 + r) * HH + h] = f2bf(acc[rg][j][r]);
            }
        }
    }
}

// ------------- Kernel 2: flash attention split-K + FUSED stream-K merge -----
// R15 = R12 attn_part (32x32x16 swapped operands, in-register P^T,
// XOR-swizzled K/V staging) + fused merge: last-arriving chunk block of each
// (b,qt) group (device-scope atomic counter) merges/normalizes the group's
// partials in-place. attn_merge kernel is gone.
template<int CH>
__global__ __launch_bounds__(256) void attn_part(const unsigned short* __restrict__ qb,
                                                 const unsigned short* __restrict__ kb,
                                                 const unsigned short* __restrict__ vbt,
                                                 unsigned short* __restrict__ Opart,
                                                 float* __restrict__ lsum,
                                                 int* __restrict__ cnt,
                                                 float* __restrict__ out) {
    __shared__ __align__(16) unsigned char smem[16912];
    unsigned short* Ks  = (unsigned short*)smem;            // 8192 B
    unsigned short* VTs = (unsigned short*)(smem + 8192);   // 8192 B
    float (*Osh)[2][16][64] = (float(*)[2][16][64])smem;    // 16384 B (reused)
    float* Lsh = (float*)(smem + 16384);                    // 512 B
    int* flag  = (int*)(smem + 16896);                      // 4 B

    constexpr int NG = 64 / CH;
    constexpr int TOTB = CH * (NG * (NG + 1)) / 2;

    const int b = blockIdx.x & 3;
    int rem = TOTB - 1 - (blockIdx.x >> 2);           // heavy-first
    int g = 0;
    while (rem >= CH * (g + 1)) { rem -= CH * (g + 1); ++g; }
    const int qt = g * CH + rem / (g + 1);
    const int ch = rem - (rem / (g + 1)) * (g + 1);

    const int q0  = qt * 64;
    const int tid = threadIdx.x;
    const int w = tid >> 6, lane = tid & 63;
    const int wq = w >> 1, wk = w & 1;
    const int l31 = lane & 31, hi = lane >> 5;

    const unsigned short* Qb  = qb  + (size_t)b * TT * HH;
    const unsigned short* Kb  = kb  + (size_t)b * TT * HH;
    const unsigned short* VTb = vbt + (size_t)b * HH * TT;

    // Q fragments (B-operand: col=q=l31, k'-octet over d)
    bf16x8 qf[4];
    {
        const unsigned short* qp = Qb + (size_t)(q0 + 32 * wq + l31) * HH + 8 * hi;
#pragma unroll
        for (int s = 0; s < 4; ++s) qf[s] = *(const bf16x8*)(qp + 16 * s);
    }

    floatx16 o0 = {}, o1 = {};            // O^T partials, d-blocks 0/1
    float lacc = 0.f;

    const int kt0 = ch * CH;
    const int kt1 = min(kt0 + CH, qt + 1);

    // staging geometry: thread covers rows sr,sr+32 at 16B slot `slot`
    const int sr = tid >> 3;              // 0..31
    const int slot = tid & 7;             // 16B slot within 128B row
    const int swz = ((slot ^ (sr & 7)) << 3);   // (sr+32)&7 == sr&7

    // swizzled read offsets (elems)
    const int kr = 32 * wk + l31;         // K row this lane consumes
    const int krow_off = kr * 64;
    const int ksw = (kr & 7);
    const int vd0 = l31, vd1 = 32 + l31;  // V^T rows (d) this lane consumes

    // prologue: first tile into regs
    u16x8 nk0, nk1, nv0, nv1;
    {
        const unsigned short* Kt = Kb + (size_t)(kt0 * 64) * HH;
        const unsigned short* Vt = VTb + kt0 * 64;
        nk0 = *(const u16x8*)(Kt + (size_t)sr * HH + slot * 8);
        nk1 = *(const u16x8*)(Kt + (size_t)(sr + 32) * HH + slot * 8);
        nv0 = *(const u16x8*)(Vt + (size_t)sr * TT + slot * 8);
        nv1 = *(const u16x8*)(Vt + (size_t)(sr + 32) * TT + slot * 8);
    }

    for (int kt = kt0; kt < kt1; ++kt) {
        __syncthreads();                  // prev-tile LDS reads done
        *(u16x8*)(Ks  + sr * 64 + swz)        = nk0;
        *(u16x8*)(Ks  + (sr + 32) * 64 + swz) = nk1;
        *(u16x8*)(VTs + sr * 64 + swz)        = nv0;
        *(u16x8*)(VTs + (sr + 32) * 64 + swz) = nv1;
        __syncthreads();                  // stage visible

        if (kt + 1 < kt1) {               // prefetch next tile (flies under compute)
            const unsigned short* Kt = Kb + (size_t)((kt + 1) * 64) * HH;
            const unsigned short* Vt = VTb + (kt + 1) * 64;
            nk0 = *(const u16x8*)(Kt + (size_t)sr * HH + slot * 8);
            nk1 = *(const u16x8*)(Kt + (size_t)(sr + 32) * HH + slot * 8);
            nv0 = *(const u16x8*)(Vt + (size_t)sr * TT + slot * 8);
            nv1 = *(const u16x8*)(Vt + (size_t)(sr + 32) * TT + slot * 8);
        }

        // K fragments from swizzled LDS
        bf16x8 kc[4];
#pragma unroll
        for (int s = 0; s < 4; ++s) {
            const int sl = 2 * s + hi;
            kc[s] = *(const bf16x8*)(Ks + krow_off + ((sl ^ ksw) << 3));
        }
        // V^T fragments from swizzled LDS
        bf16x8 vv[4];
#pragma unroll
        for (int i = 0; i < 4; ++i) {
            const int db = i >> 1, m = i & 1;
            const int d = db ? vd1 : vd0;
            const int sl = 4 * wk + 2 * m + hi;
            vv[i] = *(const bf16x8*)(VTs + d * 64 + ((sl ^ (d & 7)) << 3));
        }

        floatx16 sa = {};
#pragma unroll
        for (int s = 0; s < 4; ++s)
            sa = __builtin_amdgcn_mfma_f32_32x32x16_bf16(kc[s], qf[s], sa, 0, 0, 0);

        float st[16];
#pragma unroll
        for (int r = 0; r < 16; ++r) st[r] = sa[r] * SC2;

        if (kt == qt) {
            const int qloc = 32 * wq + l31;
#pragma unroll
            for (int r = 0; r < 16; ++r) {
                const int kloc = 32 * wk + (r & 3) + 8 * (r >> 2) + 4 * hi;
                if (kloc > qloc) st[r] = -INFINITY;
            }
        }

#pragma unroll
        for (int r = 0; r < 16; ++r) {
            const float p = exp2f(st[r]);  // == exp(raw_s); exp2(-inf)=0
            st[r] = p;
            lacc += p;
        }

        // Assemble P^T B-frags: own cvt_pk dwords + partner via shfl_xor(32)
        bf16x8 pf[2];
#pragma unroll
        for (int m = 0; m < 2; ++m) {
            const unsigned d0 = cvtpk(st[8 * m + 0], st[8 * m + 1]);
            const unsigned d1 = cvtpk(st[8 * m + 2], st[8 * m + 3]);
            const unsigned d2 = cvtpk(st[8 * m + 4], st[8 * m + 5]);
            const unsigned d3 = cvtpk(st[8 * m + 6], st[8 * m + 7]);
            const unsigned e0 = (unsigned)__shfl_xor((int)d0, 32);
            const unsigned e1 = (unsigned)__shfl_xor((int)d1, 32);
            const unsigned e2 = (unsigned)__shfl_xor((int)d2, 32);
            const unsigned e3 = (unsigned)__shfl_xor((int)d3, 32);
            union { unsigned u[4]; bf16x8 v; } pk;
            pk.u[0] = hi ? e2 : d0;
            pk.u[1] = hi ? e3 : d1;
            pk.u[2] = hi ? d2 : e0;
            pk.u[3] = hi ? d3 : e1;
            pf[m] = pk.v;
        }

        o0 = __builtin_amdgcn_mfma_f32_32x32x16_bf16(vv[0], pf[0], o0, 0, 0, 0);
        o0 = __builtin_amdgcn_mfma_f32_32x32x16_bf16(vv[1], pf[1], o0, 0, 0, 0);
        o1 = __builtin_amdgcn_mfma_f32_32x32x16_bf16(vv[2], pf[0], o1, 0, 0, 0);
        o1 = __builtin_amdgcn_mfma_f32_32x32x16_bf16(vv[3], pf[1], o1, 0, 0, 0);
    }

    // cross-wk merge through (aliased) LDS
    __syncthreads();                      // all waves done with Ks/VTs
    if (wk == 1) {
#pragma unroll
        for (int r = 0; r < 16; ++r) {
            Osh[wq][0][r][lane] = o0[r];
            Osh[wq][1][r][lane] = o1[r];
        }
        Lsh[wq * 64 + lane] = lacc;
    }
    __syncthreads();
    if (wk == 0) {
#pragma unroll
        for (int r = 0; r < 16; ++r) {
            o0[r] += Osh[wq][0][r][lane];
            o1[r] += Osh[wq][1][r][lane];
        }
        lacc += Lsh[wq * 64 + lane];
    }
    const float l = lacc + __shfl_xor(lacc, 32);

    if (qt < CH) {
        // single-chunk q-tile: normalize and write out directly
        if (wk == 0) {
            float* outp = out + ((size_t)b * TT + q0 + 32 * wq + l31) * HH;
            const float inv = 1.f / l;
#pragma unroll
            for (int r = 0; r < 16; ++r) {
                const int dd = (r & 3) + 8 * (r >> 2) + 4 * hi;
                outp[dd]      = o0[r] * inv;
                outp[32 + dd] = o1[r] * inv;
            }
        }
        return;
    }

    // multi-chunk: wk==0 waves write partials; ALL threads join the protocol
    const int pbase = ((b * 64 + qt) * NG + ch) * 64;
    if (wk == 0) {
        unsigned short* Op = Opart + ((size_t)pbase + 32 * wq + l31) * HH;
#pragma unroll
        for (int a = 0; a < 4; ++a) {
            *(unsigned*)(Op + 8 * a + 4 * hi)          = cvtpk(o0[4 * a + 0], o0[4 * a + 1]);
            *(unsigned*)(Op + 8 * a + 4 * hi + 2)      = cvtpk(o0[4 * a + 2], o0[4 * a + 3]);
            *(unsigned*)(Op + 32 + 8 * a + 4 * hi)     = cvtpk(o1[4 * a + 0], o1[4 * a + 1]);
            *(unsigned*)(Op + 32 + 8 * a + 4 * hi + 2) = cvtpk(o1[4 * a + 2], o1[4 * a + 3]);
        }
        if (hi == 0) lsum[pbase + 32 * wq + l31] = l;
    }

    const int nchunk = qt / CH + 1;
    __syncthreads();                      // all partial stores drained (vmcnt0)
    if (tid == 0) {
        __threadfence();                  // release partials device-wide
        const int old = atomicAdd(&cnt[b * 64 + qt], 1);
        *flag = (old == nchunk - 1);
    }
    __syncthreads();
    if (!*flag) return;
    __threadfence();                      // acquire: see all groups' partials

    // last-arriving block merges this (b,qt) group: 64 rows x 64 dims
    const int gbase = (b * 64 + qt) * NG * 64;
    const int oct = tid & 7, d0m = oct * 8;
#pragma unroll
    for (int pass = 0; pass < 2; ++pass) {
        const int rr = (tid >> 3) + 32 * pass;
        float L = 0.f;
        float a[8] = {};
        for (int c = 0; c < nchunk; ++c) {
            const int idx = gbase + c * 64 + rr;
            L += lsum[idx];
            const u16x8 pv = *(const u16x8*)(Opart + (size_t)idx * HH + d0m);
#pragma unroll
            for (int k = 0; k < 8; ++k) a[k] += bf2f(pv[k]);
        }
        const float inv = 1.f / L;
        float4 v0, v1;
        v0.x = a[0] * inv; v0.y = a[1] * inv; v0.z = a[2] * inv; v0.w = a[3] * inv;
        v1.x = a[4] * inv; v1.y = a[5] * inv; v1.z = a[6] * inv; v1.w = a[7] * inv;
        float* dst = out + ((size_t)b * TT + q0 + rr) * HH + d0m;
        *(float4*)(dst) = v0;
        *(float4*)(dst + 4) = v1;
    }
}

// ------------- Fallback: single-pass attention (R8 staged form) -------------
__global__ __launch_bounds__(256) void attn_full(const unsigned short* __restrict__ qb,
                                                 const unsigned short* __restrict__ kb,
                                                 const unsigned short* __restrict__ vbt,
                                                 float* __restrict__ out) {
    __shared__ unsigned short Ks[64 * LDP];
    __shared__ unsigned short VTs[64 * LDP];
    __shared__ unsigned short Ps[4][16 * LDP];

    const int b   = blockIdx.x >> 6;
    const int qt  = blockIdx.x & 63;
    const int q0  = qt * 64;
    const int tid = threadIdx.x;
    const int w = tid >> 6, lane = tid & 63;
    const int l15 = lane & 15, quad = lane >> 4;

    const unsigned short* Qb  = qb  + (size_t)b * TT * HH;
    const unsigned short* Kb  = kb  + (size_t)b * TT * HH;
    const unsigned short* VTb = vbt + (size_t)b * HH * TT;

    const int qrow = q0 + 16 * w + l15;
    const bf16x8 qf0 = *(const bf16x8*)(Qb + (size_t)qrow * HH + quad * 8);
    const bf16x8 qf1 = *(const bf16x8*)(Qb + (size_t)qrow * HH + 32 + quad * 8);

    floatx4 O[4] = {};
    floatx4 lacc = {0.f, 0.f, 0.f, 0.f};

    for (int kt = 0; kt <= qt; ++kt) {
        __syncthreads();
        const unsigned short* Kt = Kb + (size_t)(kt * 64) * HH;
        const unsigned short* Vt = VTb + kt * 64;
#pragma unroll
        for (int e = 0; e < 2; ++e) {
            const int chunk = tid + 256 * e;
            const int r = chunk >> 3, c0 = (chunk & 7) * 8;
            *(u16x8*)(Ks + r * LDP + c0)  = *(const u16x8*)(Kt + r * HH + c0);
            *(u16x8*)(VTs + r * LDP + c0) = *(const u16x8*)(Vt + (size_t)r * TT + c0);
        }
        __syncthreads();

        floatx4 s[4];
#pragma unroll
        for (int ki = 0; ki < 4; ++ki) {
            const bf16x8 kf0 = *(const bf16x8*)(Ks + (16 * ki + l15) * LDP + quad * 8);
            const bf16x8 kf1 = *(const bf16x8*)(Ks + (16 * ki + l15) * LDP + 32 + quad * 8);
            floatx4 c = {};
            c = __builtin_amdgcn_mfma_f32_16x16x32_bf16(qf0, kf0, c, 0, 0, 0);
            c = __builtin_amdgcn_mfma_f32_16x16x32_bf16(qf1, kf1, c, 0, 0, 0);
            s[ki] = c * SC2;
        }
        if (kt == qt) {
#pragma unroll
            for (int ki = 0; ki < 4; ++ki)
#pragma unroll
                for (int r = 0; r < 4; ++r)
                    if (16 * ki + l15 > 16 * w + quad * 4 + r) s[ki][r] = -INFINITY;
        }
#pragma unroll
        for (int ki = 0; ki < 4; ++ki)
#pragma unroll
            for (int r = 0; r < 4; ++r) {
                const float p = exp2f(s[ki][r]);
                s[ki][r] = p; lacc[r] += p;
            }

        unsigned short* Pw = Ps[w];
#pragma unroll
        for (int ki = 0; ki < 4; ++ki)
#pragma unroll
            for (int r = 0; r < 4; ++r)
                Pw[(quad * 4 + r) * LDP + 16 * ki + l15] = f2bf(s[ki][r]);

        const bf16x8 pf0 = *(const bf16x8*)(Pw + l15 * LDP + quad * 8);
        const bf16x8 pf1 = *(const bf16x8*)(Pw + l15 * LDP + 32 + quad * 8);
#pragma unroll
        for (int di = 0; di < 4; ++di) {
            const bf16x8 vf0 = *(const bf16x8*)(VTs + (16 * di + l15) * LDP + quad * 8);
            const bf16x8 vf1 = *(const bf16x8*)(VTs + (16 * di + l15) * LDP + 32 + quad * 8);
            O[di] = __builtin_amdgcn_mfma_f32_16x16x32_bf16(pf0, vf0, O[di], 0, 0, 0);
            O[di] = __builtin_amdgcn_mfma_f32_16x16x32_bf16(pf1, vf1, O[di], 0, 0, 0);
        }
    }
    float l_r[4];
#pragma unroll
    for (int r = 0; r < 4; ++r) {
        float v = lacc[r];
#pragma unroll
        for (int msk = 8; msk >= 1; msk >>= 1) v += __shfl_xor(v, msk, 64);
        l_r[r] = v;
    }
    float* outp = out + ((size_t)b * TT + q0 + 16 * w) * HH;
#pragma unroll
    for (int di = 0; di < 4; ++di)
#pragma unroll
        for (int r = 0; r < 4; ++r)
            outp[(quad * 4 + r) * HH + 16 * di + l15] = O[di][r] / l_r[r];
}

extern "C" void kernel_launch(void* const* d_in, const int* in_sizes, int n_in,
                              void* d_out, int out_size, void* d_ws, size_t ws_size,
                              hipStream_t stream) {
    const float* x  = (const float*)d_in[0];
    const float* Wq = (const float*)d_in[1];
    const float* Wk = (const float*)d_in[2];
    const float* Wv = (const float*)d_in[3];
    float* out = (float*)d_out;

    const size_t nQKV = (size_t)BB * TT * HH;           // 1 Mi elems
    unsigned short* qb  = (unsigned short*)d_ws;
    unsigned short* kb  = qb + nQKV;
    unsigned short* vbt = kb + nQKV;
    unsigned short* wtf = vbt + nQKV;                   // NN*CC ushorts
    unsigned short* Opart = wtf + (size_t)NN * CC;      // bf16 partials

    const size_t prows8  = (size_t)BB * 64 * 8 * 64;
    const size_t prows16 = (size_t)BB * 64 * 4 * 64;
    float* lsum8  = (float*)(Opart + prows8 * HH);
    float* lsum16 = (float*)(Opart + prows16 * HH);
    int* cnt8  = (int*)(lsum8 + prows8);
    int* cnt16 = (int*)(lsum16 + prows16);
    const size_t need8  = (size_t)((char*)(cnt8  + 256) - (char*)d_ws);
    const size_t need16 = (size_t)((char*)(cnt16 + 256) - (char*)d_ws);

    if (ws_size >= need8) {
        wprep<<<(NN * CC + 255) / 256, 256, 0, stream>>>(Wq, Wk, Wv, wtf, cnt8);
        qkv_gemm<<<(BB * TT) / GR, 256, 0, stream>>>(x, wtf, qb, kb, vbt);
        attn_part<8><<<BB * 288, 256, 0, stream>>>(qb, kb, vbt, Opart, lsum8, cnt8, out);
    } else if (ws_size >= need16) {
        wprep<<<(NN * CC + 255) / 256, 256, 0, stream>>>(Wq, Wk, Wv, wtf, cnt16);
        qkv_gemm<<<(BB * TT) / GR, 256, 0, stream>>>(x, wtf, qb, kb, vbt);
        attn_part<16><<<BB * 160, 256, 0, stream>>>(qb, kb, vbt, Opart, lsum16, cnt16, out);
    } else {
        wprep<<<(NN * CC + 255) / 256, 256, 0, stream>>>(Wq, Wk, Wv, wtf, (int*)wtf);
        qkv_gemm<<<(BB * TT) / GR, 256, 0, stream>>>(x, wtf, qb, kb, vbt);
        attn_full<<<BB * (TT / 64), 256, 0, stream>>>(qb, kb, vbt, out);
    }
}

// Round 8
// 128.919 us; speedup vs baseline: 1.7196x; 1.7196x over previous
//
#include <hip/hip_runtime.h>
#include <math.h>

#define BB 4
#define TT 4096
#define CC 768
#define HH 64
#define NN 192   // 3*HH output cols of fused QKV GEMM
#define LDP 72   // padded LDS row stride in bf16 elems (attn_full fallback)
#define GR 32    // rows per qkv_gemm block (R12 proven)
#define XSTR 776 // qkv A-tile LDS row stride (97*8 elems, 16B-aligned)
#define SC2 0.180336880f   // 0.125 * log2(e): QK scale folded with exp->exp2

typedef __bf16 bf16x8 __attribute__((ext_vector_type(8)));
typedef float floatx4 __attribute__((ext_vector_type(4)));
typedef float floatx16 __attribute__((ext_vector_type(16)));
typedef unsigned short u16x8 __attribute__((ext_vector_type(8)));

__device__ inline unsigned short f2bf(float f) {
    union { __bf16 b; unsigned short u; } v;
    v.b = (__bf16)f;                      // hw cvt (RTNE) on gfx950
    return v.u;
}
__device__ inline float bf2f(unsigned short u) {
    union { unsigned int u; float f; } v;
    v.u = (unsigned int)u << 16;
    return v.f;
}
__device__ inline unsigned cvtpk(float lo, float hi) {
    unsigned d;
    asm("v_cvt_pk_bf16_f32 %0, %1, %2" : "=v"(d) : "v"(lo), "v"(hi));
    return d;
}

// ---------------- Kernel 0: W prep — fragment-order B ----------------------
__global__ __launch_bounds__(256) void wprep(const float* __restrict__ Wq,
                                             const float* __restrict__ Wk,
                                             const float* __restrict__ Wv,
                                             unsigned short* __restrict__ wtf) {
    const int idx = blockIdx.x * 256 + threadIdx.x;
    if (idx >= NN * CC) return;
    const int j = idx & 7;
    const int lane = (idx >> 3) & 63;
    const int rest = idx >> 9;              // 0..287
    const int kg = rest % 24;
    const int n_tile = rest / 24;
    const int c = kg * 32 + (lane >> 4) * 8 + j;
    const int n = n_tile * 16 + (lane & 15);
    const float* W = (n < 64) ? Wq : (n < 128) ? Wk : Wv;
    wtf[idx] = f2bf(W[c * HH + (n & 63)]);
}

// ---------------- Kernel 1: fused QKV projection MFMA GEMM (R12/GR32) -------
__global__ __launch_bounds__(256) void qkv_gemm(const float* __restrict__ x,
                                                const unsigned short* __restrict__ wtf,
                                                unsigned short* __restrict__ qb,
                                                unsigned short* __restrict__ kb,
                                                unsigned short* __restrict__ vbt) {
    __shared__ unsigned short As[GR * XSTR];  // 48.5 KB

    const int tid = threadIdx.x;
    const int w = tid >> 6, lane = tid & 63;
    const int l15 = lane & 15, quad = lane >> 4;
    const int m0 = blockIdx.x * GR;
    const int n0 = w * 48;
    const int nt0 = w * 3;

    const float* xbase = x + (size_t)m0 * CC;
#pragma unroll
    for (int e = 0; e < 12; ++e) {
        const int c = tid + 256 * e;          // 0..3071
        const int r = c / 96, off = (c - r * 96) * 8;
        const float4 v0 = *(const float4*)(xbase + (size_t)c * 8);
        const float4 v1 = *(const float4*)(xbase + (size_t)c * 8 + 4);
        u16x8 pk;
        pk[0] = f2bf(v0.x); pk[1] = f2bf(v0.y); pk[2] = f2bf(v0.z); pk[3] = f2bf(v0.w);
        pk[4] = f2bf(v1.x); pk[5] = f2bf(v1.y); pk[6] = f2bf(v1.z); pk[7] = f2bf(v1.w);
        *(u16x8*)(As + r * XSTR + off) = pk;
    }
    __syncthreads();                          // the ONLY barrier

    floatx4 acc[2][3] = {};
#pragma unroll 4
    for (int step = 0; step < 12; ++step) {
        bf16x8 a0[2], a1[2];
#pragma unroll
        for (int rg = 0; rg < 2; ++rg) {
            const unsigned short* ap = As + (16 * rg + l15) * XSTR + step * 64 + quad * 8;
            a0[rg] = *(const bf16x8*)(ap);
            a1[rg] = *(const bf16x8*)(ap + 32);
        }
#pragma unroll
        for (int j = 0; j < 3; ++j) {
            const unsigned short* bp =
                wtf + ((size_t)((nt0 + j) * 24 + 2 * step) * 64 + lane) * 8;
            const bf16x8 b0 = *(const bf16x8*)(bp);
            const bf16x8 b1 = *(const bf16x8*)(bp + 512);
#pragma unroll
            for (int rg = 0; rg < 2; ++rg) {
                acc[rg][j] = __builtin_amdgcn_mfma_f32_16x16x32_bf16(a0[rg], b0, acc[rg][j], 0, 0, 0);
                acc[rg][j] = __builtin_amdgcn_mfma_f32_16x16x32_bf16(a1[rg], b1, acc[rg][j], 0, 0, 0);
            }
        }
    }

    const int b = m0 >> 12;
#pragma unroll
    for (int j = 0; j < 3; ++j) {
        const int n = n0 + j * 16 + l15;
        const int mid = n >> 6;                  // 0=Q,1=K,2=V
        const int h = n & 63;
#pragma unroll
        for (int rg = 0; rg < 2; ++rg) {
            const int tloc = (m0 & (TT - 1)) + 16 * rg + quad * 4;
            if (mid == 2) {
                ushort4 pk;
                pk.x = f2bf(acc[rg][j][0]); pk.y = f2bf(acc[rg][j][1]);
                pk.z = f2bf(acc[rg][j][2]); pk.w = f2bf(acc[rg][j][3]);
                *(ushort4*)(vbt + ((size_t)b * HH + h) * TT + tloc) = pk;
            } else {
                unsigned short* dst = (mid == 0) ? qb : kb;
#pragma unroll
                for (int r = 0; r < 4; ++r)
                    dst[(size_t)(m0 + 16 * rg + quad * 4 + r) * HH + h] = f2bf(acc[rg][j][r]);
            }
        }
    }
}

// ------------- Kernel 2a: flash attention phase 1 (split-K partials) --------
// R16: 128-row q-tiles, 4 waves = 4 q-sub-tiles (NO wk split).
//  - Each staged 16KB K/V tile feeds 64 MFMA (2x R12's intensity); staging
//    bytes and barriers per unit work halve.
//  - No cross-wave merge at all: each wave owns its 32 q-rows end-to-end.
//  - 32-aligned causal masking: k-subtile (32 keys) is fully-visible
//    (kb<qbase), diagonal (kb==qbase: mask key>l31), or wave-uniform skip.
//  - Compute per subtile: R12's verified swapped 32x32x16 pipeline.
template<int CH>
__global__ __launch_bounds__(256) void attn_part(const unsigned short* __restrict__ qb,
                                                 const unsigned short* __restrict__ kb,
                                                 const unsigned short* __restrict__ vbt,
                                                 unsigned short* __restrict__ Opart,
                                                 float* __restrict__ lsum,
                                                 float* __restrict__ out) {
    __shared__ __align__(16) unsigned short Ks[64 * 64];   // 8192 B
    __shared__ __align__(16) unsigned short VTs[64 * 64];  // 8192 B

    constexpr int W  = CH / 2;            // q-band width (groups per band)
    constexpr int NB = 32 / W;            // number of bands; also max chunks
    constexpr int NG = NB;
    constexpr int TOTB = W * NB * (NB + 1) / 2;

    const int b = blockIdx.x & 3;
    int rem = TOTB - 1 - (blockIdx.x >> 2);           // heavy-first
    int g = 0;
    while (rem >= W * (g + 1)) { rem -= W * (g + 1); ++g; }
    const int qt = g * W + rem / (g + 1);             // 128-row q-tile idx
    const int ch = rem - (rem / (g + 1)) * (g + 1);   // chunk idx (0..g)

    const int q0  = qt * 128;
    const int tid = threadIdx.x;
    const int w = tid >> 6, lane = tid & 63;          // w = wq (0..3)
    const int l31 = lane & 31, hi = lane >> 5;
    const int qbase = q0 + 32 * w;                    // wave's q-row base

    const unsigned short* Qb  = qb  + (size_t)b * TT * HH;
    const unsigned short* Kb  = kb  + (size_t)b * TT * HH;
    const unsigned short* VTb = vbt + (size_t)b * HH * TT;

    // Q fragments (B-operand: col=q=l31, k'-octet over d)
    bf16x8 qf[4];
    {
        const unsigned short* qp = Qb + (size_t)(qbase + l31) * HH + 8 * hi;
#pragma unroll
        for (int s = 0; s < 4; ++s) qf[s] = *(const bf16x8*)(qp + 16 * s);
    }

    floatx16 o0 = {}, o1 = {};            // O^T partials, d-blocks 0/1
    float lacc = 0.f;

    const int nkt = 2 * qt + 2;           // k-tiles this q-tile needs
    const int kt0 = ch * CH;
    const int kt1 = min(kt0 + CH, nkt);

    // staging geometry: thread covers rows sr,sr+32 at 16B slot `slot`
    const int sr = tid >> 3;              // 0..31
    const int slot = tid & 7;             // 16B slot within 128B row
    const int swz = ((slot ^ (sr & 7)) << 3);   // (sr+32)&7 == sr&7

    const int krow_off0 = l31 * 64;       // K row l31 (subtile adds 32*64)
    const int ksw = (l31 & 7);
    const int vd0 = l31, vd1 = 32 + l31;  // V^T rows (d) this lane consumes

    // prologue: first tile into regs
    u16x8 nk0, nk1, nv0, nv1;
    {
        const unsigned short* Kt = Kb + (size_t)(kt0 * 64) * HH;
        const unsigned short* Vt = VTb + kt0 * 64;
        nk0 = *(const u16x8*)(Kt + (size_t)sr * HH + slot * 8);
        nk1 = *(const u16x8*)(Kt + (size_t)(sr + 32) * HH + slot * 8);
        nv0 = *(const u16x8*)(Vt + (size_t)sr * TT + slot * 8);
        nv1 = *(const u16x8*)(Vt + (size_t)(sr + 32) * TT + slot * 8);
    }

    for (int kt = kt0; kt < kt1; ++kt) {
        __syncthreads();                  // prev-tile LDS reads done
        *(u16x8*)(Ks  + sr * 64 + swz)        = nk0;
        *(u16x8*)(Ks  + (sr + 32) * 64 + swz) = nk1;
        *(u16x8*)(VTs + sr * 64 + swz)        = nv0;
        *(u16x8*)(VTs + (sr + 32) * 64 + swz) = nv1;
        __syncthreads();                  // stage visible

        if (kt + 1 < kt1) {               // prefetch next tile (flies under compute)
            const unsigned short* Kt = Kb + (size_t)((kt + 1) * 64) * HH;
            const unsigned short* Vt = VTb + (kt + 1) * 64;
            nk0 = *(const u16x8*)(Kt + (size_t)sr * HH + slot * 8);
            nk1 = *(const u16x8*)(Kt + (size_t)(sr + 32) * HH + slot * 8);
            nv0 = *(const u16x8*)(Vt + (size_t)sr * TT + slot * 8);
            nv1 = *(const u16x8*)(Vt + (size_t)(sr + 32) * TT + slot * 8);
        }

#pragma unroll
        for (int ks = 0; ks < 2; ++ks) {  // two 32-key subtiles
            const int kb32 = kt * 64 + 32 * ks;
            if (kb32 > qbase + 31) continue;      // wave-uniform skip

            // K fragments from swizzled LDS (rows 32*ks + l31)
            bf16x8 kc[4];
#pragma unroll
            for (int s = 0; s < 4; ++s) {
                const int sl = 2 * s + hi;
                kc[s] = *(const bf16x8*)(Ks + 32 * 64 * ks + krow_off0 + ((sl ^ ksw) << 3));
            }

            floatx16 sa = {};
#pragma unroll
            for (int s = 0; s < 4; ++s)
                sa = __builtin_amdgcn_mfma_f32_32x32x16_bf16(kc[s], qf[s], sa, 0, 0, 0);

            float st[16];
#pragma unroll
            for (int r = 0; r < 16; ++r) st[r] = sa[r] * SC2;

            if (kb32 == qbase) {          // diagonal subtile: 32-aligned mask
#pragma unroll
                for (int r = 0; r < 16; ++r) {
                    const int key = (r & 3) + 8 * (r >> 2) + 4 * hi;
                    if (key > l31) st[r] = -INFINITY;
                }
            }

#pragma unroll
            for (int r = 0; r < 16; ++r) {
                const float p = exp2f(st[r]);  // == exp(raw_s); exp2(-inf)=0
                st[r] = p;
                lacc += p;
            }

            // P^T B-frags: own cvt_pk dwords + partner via shfl_xor(32)
            bf16x8 pf[2];
#pragma unroll
            for (int m = 0; m < 2; ++m) {
                const unsigned d0 = cvtpk(st[8 * m + 0], st[8 * m + 1]);
                const unsigned d1 = cvtpk(st[8 * m + 2], st[8 * m + 3]);
                const unsigned d2 = cvtpk(st[8 * m + 4], st[8 * m + 5]);
                const unsigned d3 = cvtpk(st[8 * m + 6], st[8 * m + 7]);
                const unsigned e0 = (unsigned)__shfl_xor((int)d0, 32);
                const unsigned e1 = (unsigned)__shfl_xor((int)d1, 32);
                const unsigned e2 = (unsigned)__shfl_xor((int)d2, 32);
                const unsigned e3 = (unsigned)__shfl_xor((int)d3, 32);
                union { unsigned u[4]; bf16x8 v; } pk;
                pk.u[0] = hi ? e2 : d0;
                pk.u[1] = hi ? e3 : d1;
                pk.u[2] = hi ? d2 : e0;
                pk.u[3] = hi ? d3 : e1;
                pf[m] = pk.v;
            }

            // V^T fragments for this subtile (cols 32*ks..+31 of tile)
            bf16x8 vv[4];
#pragma unroll
            for (int i = 0; i < 4; ++i) {
                const int db = i >> 1, m = i & 1;
                const int d = db ? vd1 : vd0;
                const int sl = 4 * ks + 2 * m + hi;
                vv[i] = *(const bf16x8*)(VTs + d * 64 + ((sl ^ (d & 7)) << 3));
            }

            o0 = __builtin_amdgcn_mfma_f32_32x32x16_bf16(vv[0], pf[0], o0, 0, 0, 0);
            o0 = __builtin_amdgcn_mfma_f32_32x32x16_bf16(vv[1], pf[1], o0, 0, 0, 0);
            o1 = __builtin_amdgcn_mfma_f32_32x32x16_bf16(vv[2], pf[0], o1, 0, 0, 0);
            o1 = __builtin_amdgcn_mfma_f32_32x32x16_bf16(vv[3], pf[1], o1, 0, 0, 0);
        }
    }

    const float l = lacc + __shfl_xor(lacc, 32);

    if (qt < W) {
        // single-chunk q-tile: normalize and write out directly (merge skips)
        float* outp = out + ((size_t)b * TT + qbase + l31) * HH;
        const float inv = 1.f / l;
#pragma unroll
        for (int r = 0; r < 16; ++r) {
            const int dd = (r & 3) + 8 * (r >> 2) + 4 * hi;
            outp[dd]      = o0[r] * inv;
            outp[32 + dd] = o1[r] * inv;
        }
        return;
    }

    const int pbase = ((b * 32 + qt) * NG + ch) * 128;
    unsigned short* Op = Opart + ((size_t)pbase + 32 * w + l31) * HH;
#pragma unroll
    for (int a = 0; a < 4; ++a) {
        *(unsigned*)(Op + 8 * a + 4 * hi)          = cvtpk(o0[4 * a + 0], o0[4 * a + 1]);
        *(unsigned*)(Op + 8 * a + 4 * hi + 2)      = cvtpk(o0[4 * a + 2], o0[4 * a + 3]);
        *(unsigned*)(Op + 32 + 8 * a + 4 * hi)     = cvtpk(o1[4 * a + 0], o1[4 * a + 1]);
        *(unsigned*)(Op + 32 + 8 * a + 4 * hi + 2) = cvtpk(o1[4 * a + 2], o1[4 * a + 3]);
    }
    if (hi == 0) lsum[pbase + 32 * w + l31] = l;
}

// ------------- Kernel 2b: merge partials (bf16, vectorized) -----------------
// Thread per (row, 8-dim octet). Rows with qt < W were written directly.
template<int CH>
__global__ __launch_bounds__(256) void attn_merge(const unsigned short* __restrict__ Opart,
                                                  const float* __restrict__ lsum,
                                                  float* __restrict__ out) {
    constexpr int W  = CH / 2;
    constexpr int NG = 32 / W;
    const int g = blockIdx.x * 256 + threadIdx.x;   // row*8 + octet
    const int row = g >> 3, oct = g & 7;
    const int b = row >> 12, t = row & (TT - 1);
    const int qt = t >> 7, rloc = t & 127;
    if (qt < W) return;                             // fast-path rows done
    const int nchunk = qt / W + 1;
    const int pbase = ((b * 32 + qt) * NG) * 128 + rloc;
    const int d0 = oct * 8;

    float L = 0.f;
    float a[8] = {};
    for (int c = 0; c < nchunk; ++c) {
        const int idx = pbase + c * 128;
        L += lsum[idx];
        const u16x8 pv = *(const u16x8*)(Opart + (size_t)idx * HH + d0);
#pragma unroll
        for (int k = 0; k < 8; ++k) a[k] += bf2f(pv[k]);
    }
    const float inv = 1.f / L;
    float4 o0, o1;
    o0.x = a[0] * inv; o0.y = a[1] * inv; o0.z = a[2] * inv; o0.w = a[3] * inv;
    o1.x = a[4] * inv; o1.y = a[5] * inv; o1.z = a[6] * inv; o1.w = a[7] * inv;
    float* dst = out + (size_t)row * HH + d0;
    *(float4*)(dst) = o0;
    *(float4*)(dst + 4) = o1;
}

// ------------- Fallback: single-pass attention (R8 staged form) -------------
__global__ __launch_bounds__(256) void attn_full(const unsigned short* __restrict__ qb,
                                                 const unsigned short* __restrict__ kb,
                                                 const unsigned short* __restrict__ vbt,
                                                 float* __restrict__ out) {
    __shared__ unsigned short Ks[64 * LDP];
    __shared__ unsigned short VTs[64 * LDP];
    __shared__ unsigned short Ps[4][16 * LDP];

    const int b   = blockIdx.x >> 6;
    const int qt  = blockIdx.x & 63;
    const int q0  = qt * 64;
    const int tid = threadIdx.x;
    const int w = tid >> 6, lane = tid & 63;
    const int l15 = lane & 15, quad = lane >> 4;

    const unsigned short* Qb  = qb  + (size_t)b * TT * HH;
    const unsigned short* Kb  = kb  + (size_t)b * TT * HH;
    const unsigned short* VTb = vbt + (size_t)b * HH * TT;

    const int qrow = q0 + 16 * w + l15;
    const bf16x8 qf0 = *(const bf16x8*)(Qb + (size_t)qrow * HH + quad * 8);
    const bf16x8 qf1 = *(const bf16x8*)(Qb + (size_t)qrow * HH + 32 + quad * 8);

    floatx4 O[4] = {};
    floatx4 lacc = {0.f, 0.f, 0.f, 0.f};

    for (int kt = 0; kt <= qt; ++kt) {
        __syncthreads();
        const unsigned short* Kt = Kb + (size_t)(kt * 64) * HH;
        const unsigned short* Vt = VTb + kt * 64;
#pragma unroll
        for (int e = 0; e < 2; ++e) {
            const int chunk = tid + 256 * e;
            const int r = chunk >> 3, c0 = (chunk & 7) * 8;
            *(u16x8*)(Ks + r * LDP + c0)  = *(const u16x8*)(Kt + r * HH + c0);
            *(u16x8*)(VTs + r * LDP + c0) = *(const u16x8*)(Vt + (size_t)r * TT + c0);
        }
        __syncthreads();

        floatx4 s[4];
#pragma unroll
        for (int ki = 0; ki < 4; ++ki) {
            const bf16x8 kf0 = *(const bf16x8*)(Ks + (16 * ki + l15) * LDP + quad * 8);
            const bf16x8 kf1 = *(const bf16x8*)(Ks + (16 * ki + l15) * LDP + 32 + quad * 8);
            floatx4 c = {};
            c = __builtin_amdgcn_mfma_f32_16x16x32_bf16(qf0, kf0, c, 0, 0, 0);
            c = __builtin_amdgcn_mfma_f32_16x16x32_bf16(qf1, kf1, c, 0, 0, 0);
            s[ki] = c * SC2;
        }
        if (kt == qt) {
#pragma unroll
            for (int ki = 0; ki < 4; ++ki)
#pragma unroll
                for (int r = 0; r < 4; ++r)
                    if (16 * ki + l15 > 16 * w + quad * 4 + r) s[ki][r] = -INFINITY;
        }
#pragma unroll
        for (int ki = 0; ki < 4; ++ki)
#pragma unroll
            for (int r = 0; r < 4; ++r) {
                const float p = exp2f(s[ki][r]);
                s[ki][r] = p; lacc[r] += p;
            }

        unsigned short* Pw = Ps[w];
#pragma unroll
        for (int ki = 0; ki < 4; ++ki)
#pragma unroll
            for (int r = 0; r < 4; ++r)
                Pw[(quad * 4 + r) * LDP + 16 * ki + l15] = f2bf(s[ki][r]);

        const bf16x8 pf0 = *(const bf16x8*)(Pw + l15 * LDP + quad * 8);
        const bf16x8 pf1 = *(const bf16x8*)(Pw + l15 * LDP + 32 + quad * 8);
#pragma unroll
        for (int di = 0; di < 4; ++di) {
            const bf16x8 vf0 = *(const bf16x8*)(VTs + (16 * di + l15) * LDP + quad * 8);
            const bf16x8 vf1 = *(const bf16x8*)(VTs + (16 * di + l15) * LDP + 32 + quad * 8);
            O[di] = __builtin_amdgcn_mfma_f32_16x16x32_bf16(pf0, vf0, O[di], 0, 0, 0);
            O[di] = __builtin_amdgcn_mfma_f32_16x16x32_bf16(pf1, vf1, O[di], 0, 0, 0);
        }
    }
    float l_r[4];
#pragma unroll
    for (int r = 0; r < 4; ++r) {
        float v = lacc[r];
#pragma unroll
        for (int msk = 8; msk >= 1; msk >>= 1) v += __shfl_xor(v, msk, 64);
        l_r[r] = v;
    }
    float* outp = out + ((size_t)b * TT + q0 + 16 * w) * HH;
#pragma unroll
    for (int di = 0; di < 4; ++di)
#pragma unroll
        for (int r = 0; r < 4; ++r)
            outp[(quad * 4 + r) * HH + 16 * di + l15] = O[di][r] / l_r[r];
}

extern "C" void kernel_launch(void* const* d_in, const int* in_sizes, int n_in,
                              void* d_out, int out_size, void* d_ws, size_t ws_size,
                              hipStream_t stream) {
    const float* x  = (const float*)d_in[0];
    const float* Wq = (const float*)d_in[1];
    const float* Wk = (const float*)d_in[2];
    const float* Wv = (const float*)d_in[3];
    float* out = (float*)d_out;

    const size_t nQKV = (size_t)BB * TT * HH;           // 1 Mi elems
    unsigned short* qb  = (unsigned short*)d_ws;
    unsigned short* kb  = qb + nQKV;
    unsigned short* vbt = kb + nQKV;
    unsigned short* wtf = vbt + nQKV;                   // NN*CC ushorts
    unsigned short* Opart = wtf + (size_t)NN * CC;      // bf16 partials

    // CH=8: 32 q-tiles x NG=8 chunks x 128 rows; CH=16: NG=4
    const size_t prows8  = (size_t)BB * 32 * 8 * 128;
    const size_t prows16 = (size_t)BB * 32 * 4 * 128;
    float* lsum8  = (float*)(Opart + prows8 * HH);
    float* lsum16 = (float*)(Opart + prows16 * HH);
    const size_t need8  = (size_t)((char*)(lsum8  + prows8)  - (char*)d_ws);
    const size_t need16 = (size_t)((char*)(lsum16 + prows16) - (char*)d_ws);

    wprep<<<(NN * CC + 255) / 256, 256, 0, stream>>>(Wq, Wk, Wv, wtf);
    qkv_gemm<<<(BB * TT) / GR, 256, 0, stream>>>(x, wtf, qb, kb, vbt);
    if (ws_size >= need8) {
        attn_part<8><<<BB * 144, 256, 0, stream>>>(qb, kb, vbt, Opart, lsum8, out);
        attn_merge<8><<<(BB * TT * 8) / 256, 256, 0, stream>>>(Opart, lsum8, out);
    } else if (ws_size >= need16) {
        attn_part<16><<<BB * 80, 256, 0, stream>>>(qb, kb, vbt, Opart, lsum16, out);
        attn_merge<16><<<(BB * TT * 8) / 256, 256, 0, stream>>>(Opart, lsum16, out);
    } else {
        attn_full<<<BB * (TT / 64), 256, 0, stream>>>(qb, kb, vbt, out);
    }
}

// Round 10
// 126.946 us; speedup vs baseline: 1.7463x; 1.0155x over previous
//
#include <hip/hip_runtime.h>
#include <math.h>

#define BB 4
#define TT 4096
#define CC 768
#define HH 64
#define NN 192   // 3*HH output cols of fused QKV GEMM
#define LDP 72   // padded LDS row stride in bf16 elems (attn_full fallback)
#define GR 32    // rows per qkv_gemm block
#define CK 192   // qkv K-chunk (cols per pipelined slice)
#define ASTR 200 // qkv A-tile LDS row stride in bf16 elems (192 + 8 pad)
#define SC2 0.180336880f   // 0.125 * log2(e): QK scale folded with exp->exp2

typedef __bf16 bf16x8 __attribute__((ext_vector_type(8)));
typedef float floatx4 __attribute__((ext_vector_type(4)));
typedef float floatx16 __attribute__((ext_vector_type(16)));
typedef unsigned short u16x8 __attribute__((ext_vector_type(8)));

__device__ inline unsigned short f2bf(float f) {
    union { __bf16 b; unsigned short u; } v;
    v.b = (__bf16)f;                      // hw cvt (RTNE) on gfx950
    return v.u;
}
__device__ inline float bf2f(unsigned short u) {
    union { unsigned int u; float f; } v;
    v.u = (unsigned int)u << 16;
    return v.f;
}
__device__ inline unsigned cvtpk(float lo, float hi) {
    unsigned d;
    asm("v_cvt_pk_bf16_f32 %0, %1, %2" : "=v"(d) : "v"(lo), "v"(hi));
    return d;
}

// ---------------- Kernel 0: W prep — fragment-order B ----------------------
__global__ __launch_bounds__(256) void wprep(const float* __restrict__ Wq,
                                             const float* __restrict__ Wk,
                                             const float* __restrict__ Wv,
                                             unsigned short* __restrict__ wtf) {
    const int idx = blockIdx.x * 256 + threadIdx.x;
    if (idx >= NN * CC) return;
    const int j = idx & 7;
    const int lane = (idx >> 3) & 63;
    const int rest = idx >> 9;              // 0..287
    const int kg = rest % 24;
    const int n_tile = rest / 24;
    const int c = kg * 32 + (lane >> 4) * 8 + j;
    const int n = n_tile * 16 + (lane & 15);
    const float* W = (n < 64) ? Wq : (n < 128) ? Wk : Wv;
    wtf[idx] = f2bf(W[c * HH + (n & 63)]);
}

// ---------------- Kernel 1: fused QKV projection MFMA GEMM ------------------
// R17: K-chunked (4 x 192) double-buffered staging. Order per chunk:
//   barrier -> compute(chunk c from buf[c&1]) -> cvt_pk+write(chunk c+1 ->
//   buf[(c+1)&1]) -> issue HBM loads(chunk c+2)
// so each chunk's HBM loads have a full 36-MFMA compute phase in flight.
// LDS 48.5 -> 25.6 KB (2 x 32 x 200 bf16) => ~6 blocks/CU capable.
// f32->bf16 conversion via v_cvt_pk (half the VALU of scalar f2bf).
__global__ __launch_bounds__(256) void qkv_gemm(const float* __restrict__ x,
                                                const unsigned short* __restrict__ wtf,
                                                unsigned short* __restrict__ qb,
                                                unsigned short* __restrict__ kb,
                                                unsigned short* __restrict__ vbt) {
    __shared__ unsigned short As[2 * GR * ASTR];  // 25.6 KB

    const int tid = threadIdx.x;
    const int w = tid >> 6, lane = tid & 63;
    const int l15 = lane & 15, quad = lane >> 4;
    const int m0 = blockIdx.x * GR;
    const int n0 = w * 48;
    const int nt0 = w * 3;

    // staging map: per chunk, 768 8-elem groups; flat = row*24 + grp keeps
    // consecutive lanes on consecutive 32B (768B-contiguous per row).
    int srow[3], sgrp[3];
#pragma unroll
    for (int g = 0; g < 3; ++g) {
        const int flat = tid + 256 * g;       // 0..767
        srow[g] = flat / 24;
        sgrp[g] = flat - srow[g] * 24;
    }

    float4 xr[6];
#define LOADC(c)                                                               \
    {                                                                          \
        _Pragma("unroll")                                                      \
        for (int g = 0; g < 3; ++g) {                                          \
            const float* p = x + (size_t)(m0 + srow[g]) * CC + (c) * CK        \
                             + sgrp[g] * 8;                                    \
            xr[2 * g]     = *(const float4*)(p);                               \
            xr[2 * g + 1] = *(const float4*)(p + 4);                           \
        }                                                                      \
    }
#define WRITEC(c)                                                              \
    {                                                                          \
        unsigned short* Ab = As + ((c) & 1) * (GR * ASTR);                     \
        _Pragma("unroll")                                                      \
        for (int g = 0; g < 3; ++g) {                                          \
            union { unsigned u[4]; u16x8 v; } pk;                              \
            pk.u[0] = cvtpk(xr[2 * g].x, xr[2 * g].y);                         \
            pk.u[1] = cvtpk(xr[2 * g].z, xr[2 * g].w);                         \
            pk.u[2] = cvtpk(xr[2 * g + 1].x, xr[2 * g + 1].y);                 \
            pk.u[3] = cvtpk(xr[2 * g + 1].z, xr[2 * g + 1].w);                 \
            *(u16x8*)(Ab + srow[g] * ASTR + sgrp[g] * 8) = pk.v;               \
        }                                                                      \
    }

    LOADC(0);
    WRITEC(0);
    LOADC(1);

    floatx4 acc[2][3] = {};
    for (int c = 0; c < 4; ++c) {
        const unsigned short* Ab = As + (c & 1) * (GR * ASTR);
        __syncthreads();                      // publish buf[c&1]; order prior reads
#pragma unroll
        for (int s = 0; s < 3; ++s) {
            bf16x8 a0[2], a1[2];
#pragma unroll
            for (int rg = 0; rg < 2; ++rg) {
                const unsigned short* ap = Ab + (16 * rg + l15) * ASTR + s * 64 + quad * 8;
                a0[rg] = *(const bf16x8*)(ap);
                a1[rg] = *(const bf16x8*)(ap + 32);
            }
            const int gstep = 3 * c + s;
#pragma unroll
            for (int j = 0; j < 3; ++j) {
                const unsigned short* bp =
                    wtf + ((size_t)((nt0 + j) * 24 + 2 * gstep) * 64 + lane) * 8;
                const bf16x8 b0 = *(const bf16x8*)(bp);
                const bf16x8 b1 = *(const bf16x8*)(bp + 512);
#pragma unroll
                for (int rg = 0; rg < 2; ++rg) {
                    acc[rg][j] = __builtin_amdgcn_mfma_f32_16x16x32_bf16(a0[rg], b0, acc[rg][j], 0, 0, 0);
                    acc[rg][j] = __builtin_amdgcn_mfma_f32_16x16x32_bf16(a1[rg], b1, acc[rg][j], 0, 0, 0);
                }
            }
        }
        if (c + 1 < 4) {
            WRITEC(c + 1);                    // waits vmcnt for chunk c+1 loads
            if (c + 2 < 4) LOADC(c + 2);      // next loads fly under next compute
        }
    }
#undef LOADC
#undef WRITEC

    const int b = m0 >> 12;
#pragma unroll
    for (int j = 0; j < 3; ++j) {
        const int n = n0 + j * 16 + l15;
        const int mid = n >> 6;                  // 0=Q,1=K,2=V
        const int h = n & 63;
#pragma unroll
        for (int rg = 0; rg < 2; ++rg) {
            const int tloc = (m0 & (TT - 1)) + 16 * rg + quad * 4;
            if (mid == 2) {
                ushort4 pk;
                pk.x = f2bf(acc[rg][j][0]); pk.y = f2bf(acc[rg][j][1]);
                pk.z = f2bf(acc[rg][j][2]); pk.w = f2bf(acc[rg][j][3]);
                *(ushort4*)(vbt + ((size_t)b * HH + h) * TT + tloc) = pk;
            } else {
                unsigned short* dst = (mid == 0) ? qb : kb;
#pragma unroll
                for (int r = 0; r < 4; ++r)
                    dst[(size_t)(m0 + 16 * rg + quad * 4 + r) * HH + h] = f2bf(acc[rg][j][r]);
            }
        }
    }
}

// ------------- Kernel 2a: flash attention phase 1 (split-K partials) --------
// R16 exact: 128-row q-tiles, 4 waves = 4 q-sub-tiles (no wk split),
// swapped 32x32x16 pipeline, XOR-swizzled staging, in-register P^T.
template<int CH>
__global__ __launch_bounds__(256) void attn_part(const unsigned short* __restrict__ qb,
                                                 const unsigned short* __restrict__ kb,
                                                 const unsigned short* __restrict__ vbt,
                                                 unsigned short* __restrict__ Opart,
                                                 float* __restrict__ lsum,
                                                 float* __restrict__ out) {
    __shared__ __align__(16) unsigned short Ks[64 * 64];   // 8192 B
    __shared__ __align__(16) unsigned short VTs[64 * 64];  // 8192 B

    constexpr int W  = CH / 2;            // q-band width (groups per band)
    constexpr int NB = 32 / W;            // number of bands; also max chunks
    constexpr int NG = NB;
    constexpr int TOTB = W * NB * (NB + 1) / 2;

    const int b = blockIdx.x & 3;
    int rem = TOTB - 1 - (blockIdx.x >> 2);           // heavy-first
    int g = 0;
    while (rem >= W * (g + 1)) { rem -= W * (g + 1); ++g; }
    const int qt = g * W + rem / (g + 1);             // 128-row q-tile idx
    const int ch = rem - (rem / (g + 1)) * (g + 1);   // chunk idx (0..g)

    const int q0  = qt * 128;
    const int tid = threadIdx.x;
    const int w = tid >> 6, lane = tid & 63;          // w = wq (0..3)
    const int l31 = lane & 31, hi = lane >> 5;
    const int qbase = q0 + 32 * w;                    // wave's q-row base

    const unsigned short* Qb  = qb  + (size_t)b * TT * HH;
    const unsigned short* Kb  = kb  + (size_t)b * TT * HH;
    const unsigned short* VTb = vbt + (size_t)b * HH * TT;

    // Q fragments (B-operand: col=q=l31, k'-octet over d)
    bf16x8 qf[4];
    {
        const unsigned short* qp = Qb + (size_t)(qbase + l31) * HH + 8 * hi;
#pragma unroll
        for (int s = 0; s < 4; ++s) qf[s] = *(const bf16x8*)(qp + 16 * s);
    }

    floatx16 o0 = {}, o1 = {};            // O^T partials, d-blocks 0/1
    float lacc = 0.f;

    const int nkt = 2 * qt + 2;           // k-tiles this q-tile needs
    const int kt0 = ch * CH;
    const int kt1 = min(kt0 + CH, nkt);

    // staging geometry: thread covers rows sr,sr+32 at 16B slot `slot`
    const int sr = tid >> 3;              // 0..31
    const int slot = tid & 7;             // 16B slot within 128B row
    const int swz = ((slot ^ (sr & 7)) << 3);   // (sr+32)&7 == sr&7

    const int krow_off0 = l31 * 64;       // K row l31 (subtile adds 32*64)
    const int ksw = (l31 & 7);
    const int vd0 = l31, vd1 = 32 + l31;  // V^T rows (d) this lane consumes

    // prologue: first tile into regs
    u16x8 nk0, nk1, nv0, nv1;
    {
        const unsigned short* Kt = Kb + (size_t)(kt0 * 64) * HH;
        const unsigned short* Vt = VTb + kt0 * 64;
        nk0 = *(const u16x8*)(Kt + (size_t)sr * HH + slot * 8);
        nk1 = *(const u16x8*)(Kt + (size_t)(sr + 32) * HH + slot * 8);
        nv0 = *(const u16x8*)(Vt + (size_t)sr * TT + slot * 8);
        nv1 = *(const u16x8*)(Vt + (size_t)(sr + 32) * TT + slot * 8);
    }

    for (int kt = kt0; kt < kt1; ++kt) {
        __syncthreads();                  // prev-tile LDS reads done
        *(u16x8*)(Ks  + sr * 64 + swz)        = nk0;
        *(u16x8*)(Ks  + (sr + 32) * 64 + swz) = nk1;
        *(u16x8*)(VTs + sr * 64 + swz)        = nv0;
        *(u16x8*)(VTs + (sr + 32) * 64 + swz) = nv1;
        __syncthreads();                  // stage visible

        if (kt + 1 < kt1) {               // prefetch next tile (flies under compute)
            const unsigned short* Kt = Kb + (size_t)((kt + 1) * 64) * HH;
            const unsigned short* Vt = VTb + (kt + 1) * 64;
            nk0 = *(const u16x8*)(Kt + (size_t)sr * HH + slot * 8);
            nk1 = *(const u16x8*)(Kt + (size_t)(sr + 32) * HH + slot * 8);
            nv0 = *(const u16x8*)(Vt + (size_t)sr * TT + slot * 8);
            nv1 = *(const u16x8*)(Vt + (size_t)(sr + 32) * TT + slot * 8);
        }

#pragma unroll
        for (int ks = 0; ks < 2; ++ks) {  // two 32-key subtiles
            const int kb32 = kt * 64 + 32 * ks;
            if (kb32 > qbase + 31) continue;      // wave-uniform skip

            // K fragments from swizzled LDS (rows 32*ks + l31)
            bf16x8 kc[4];
#pragma unroll
            for (int s = 0; s < 4; ++s) {
                const int sl = 2 * s + hi;
                kc[s] = *(const bf16x8*)(Ks + 32 * 64 * ks + krow_off0 + ((sl ^ ksw) << 3));
            }

            floatx16 sa = {};
#pragma unroll
            for (int s = 0; s < 4; ++s)
                sa = __builtin_amdgcn_mfma_f32_32x32x16_bf16(kc[s], qf[s], sa, 0, 0, 0);

            float st[16];
#pragma unroll
            for (int r = 0; r < 16; ++r) st[r] = sa[r] * SC2;

            if (kb32 == qbase) {          // diagonal subtile: 32-aligned mask
#pragma unroll
                for (int r = 0; r < 16; ++r) {
                    const int key = (r & 3) + 8 * (r >> 2) + 4 * hi;
                    if (key > l31) st[r] = -INFINITY;
                }
            }

#pragma unroll
            for (int r = 0; r < 16; ++r) {
                const float p = exp2f(st[r]);  // == exp(raw_s); exp2(-inf)=0
                st[r] = p;
                lacc += p;
            }

            // P^T B-frags: own cvt_pk dwords + partner via shfl_xor(32)
            bf16x8 pf[2];
#pragma unroll
            for (int m = 0; m < 2; ++m) {
                const unsigned d0 = cvtpk(st[8 * m + 0], st[8 * m + 1]);
                const unsigned d1 = cvtpk(st[8 * m + 2], st[8 * m + 3]);
                const unsigned d2 = cvtpk(st[8 * m + 4], st[8 * m + 5]);
                const unsigned d3 = cvtpk(st[8 * m + 6], st[8 * m + 7]);
                const unsigned e0 = (unsigned)__shfl_xor((int)d0, 32);
                const unsigned e1 = (unsigned)__shfl_xor((int)d1, 32);
                const unsigned e2 = (unsigned)__shfl_xor((int)d2, 32);
                const unsigned e3 = (unsigned)__shfl_xor((int)d3, 32);
                union { unsigned u[4]; bf16x8 v; } pk;
                pk.u[0] = hi ? e2 : d0;
                pk.u[1] = hi ? e3 : d1;
                pk.u[2] = hi ? d2 : e0;
                pk.u[3] = hi ? d3 : e1;
                pf[m] = pk.v;
            }

            // V^T fragments for this subtile (cols 32*ks..+31 of tile)
            bf16x8 vv[4];
#pragma unroll
            for (int i = 0; i < 4; ++i) {
                const int db = i >> 1, m = i & 1;
                const int d = db ? vd1 : vd0;
                const int sl = 4 * ks + 2 * m + hi;
                vv[i] = *(const bf16x8*)(VTs + d * 64 + ((sl ^ (d & 7)) << 3));
            }

            o0 = __builtin_amdgcn_mfma_f32_32x32x16_bf16(vv[0], pf[0], o0, 0, 0, 0);
            o0 = __builtin_amdgcn_mfma_f32_32x32x16_bf16(vv[1], pf[1], o0, 0, 0, 0);
            o1 = __builtin_amdgcn_mfma_f32_32x32x16_bf16(vv[2], pf[0], o1, 0, 0, 0);
            o1 = __builtin_amdgcn_mfma_f32_32x32x16_bf16(vv[3], pf[1], o1, 0, 0, 0);
        }
    }

    const float l = lacc + __shfl_xor(lacc, 32);

    if (qt < W) {
        // single-chunk q-tile: normalize and write out directly (merge skips)
        float* outp = out + ((size_t)b * TT + qbase + l31) * HH;
        const float inv = 1.f / l;
#pragma unroll
        for (int r = 0; r < 16; ++r) {
            const int dd = (r & 3) + 8 * (r >> 2) + 4 * hi;
            outp[dd]      = o0[r] * inv;
            outp[32 + dd] = o1[r] * inv;
        }
        return;
    }

    const int pbase = ((b * 32 + qt) * NG + ch) * 128;
    unsigned short* Op = Opart + ((size_t)pbase + 32 * w + l31) * HH;
#pragma unroll
    for (int a = 0; a < 4; ++a) {
        *(unsigned*)(Op + 8 * a + 4 * hi)          = cvtpk(o0[4 * a + 0], o0[4 * a + 1]);
        *(unsigned*)(Op + 8 * a + 4 * hi + 2)      = cvtpk(o0[4 * a + 2], o0[4 * a + 3]);
        *(unsigned*)(Op + 32 + 8 * a + 4 * hi)     = cvtpk(o1[4 * a + 0], o1[4 * a + 1]);
        *(unsigned*)(Op + 32 + 8 * a + 4 * hi + 2) = cvtpk(o1[4 * a + 2], o1[4 * a + 3]);
    }
    if (hi == 0) lsum[pbase + 32 * w + l31] = l;
}

// ------------- Kernel 2b: merge partials (bf16, vectorized) -----------------
// Thread per (row, 8-dim octet). Rows with qt < W were written directly.
template<int CH>
__global__ __launch_bounds__(256) void attn_merge(const unsigned short* __restrict__ Opart,
                                                  const float* __restrict__ lsum,
                                                  float* __restrict__ out) {
    constexpr int W  = CH / 2;
    constexpr int NG = 32 / W;
    const int g = blockIdx.x * 256 + threadIdx.x;   // row*8 + octet
    const int row = g >> 3, oct = g & 7;
    const int b = row >> 12, t = row & (TT - 1);
    const int qt = t >> 7, rloc = t & 127;
    if (qt < W) return;                             // fast-path rows done
    const int nchunk = qt / W + 1;
    const int pbase = ((b * 32 + qt) * NG) * 128 + rloc;
    const int d0 = oct * 8;

    float L = 0.f;
    float a[8] = {};
    for (int c = 0; c < nchunk; ++c) {
        const int idx = pbase + c * 128;
        L += lsum[idx];
        const u16x8 pv = *(const u16x8*)(Opart + (size_t)idx * HH + d0);
#pragma unroll
        for (int k = 0; k < 8; ++k) a[k] += bf2f(pv[k]);
    }
    const float inv = 1.f / L;
    float4 o0, o1;
    o0.x = a[0] * inv; o0.y = a[1] * inv; o0.z = a[2] * inv; o0.w = a[3] * inv;
    o1.x = a[4] * inv; o1.y = a[5] * inv; o1.z = a[6] * inv; o1.w = a[7] * inv;
    float* dst = out + (size_t)row * HH + d0;
    *(float4*)(dst) = o0;
    *(float4*)(dst + 4) = o1;
}

// ------------- Fallback: single-pass attention (R8 staged form) -------------
__global__ __launch_bounds__(256) void attn_full(const unsigned short* __restrict__ qb,
                                                 const unsigned short* __restrict__ kb,
                                                 const unsigned short* __restrict__ vbt,
                                                 float* __restrict__ out) {
    __shared__ unsigned short Ks[64 * LDP];
    __shared__ unsigned short VTs[64 * LDP];
    __shared__ unsigned short Ps[4][16 * LDP];

    const int b   = blockIdx.x >> 6;
    const int qt  = blockIdx.x & 63;
    const int q0  = qt * 64;
    const int tid = threadIdx.x;
    const int w = tid >> 6, lane = tid & 63;
    const int l15 = lane & 15, quad = lane >> 4;

    const unsigned short* Qb  = qb  + (size_t)b * TT * HH;
    const unsigned short* Kb  = kb  + (size_t)b * TT * HH;
    const unsigned short* VTb = vbt + (size_t)b * HH * TT;

    const int qrow = q0 + 16 * w + l15;
    const bf16x8 qf0 = *(const bf16x8*)(Qb + (size_t)qrow * HH + quad * 8);
    const bf16x8 qf1 = *(const bf16x8*)(Qb + (size_t)qrow * HH + 32 + quad * 8);

    floatx4 O[4] = {};
    floatx4 lacc = {0.f, 0.f, 0.f, 0.f};

    for (int kt = 0; kt <= qt; ++kt) {
        __syncthreads();
        const unsigned short* Kt = Kb + (size_t)(kt * 64) * HH;
        const unsigned short* Vt = VTb + kt * 64;
#pragma unroll
        for (int e = 0; e < 2; ++e) {
            const int chunk = tid + 256 * e;
            const int r = chunk >> 3, c0 = (chunk & 7) * 8;
            *(u16x8*)(Ks + r * LDP + c0)  = *(const u16x8*)(Kt + r * HH + c0);
            *(u16x8*)(VTs + r * LDP + c0) = *(const u16x8*)(Vt + (size_t)r * TT + c0);
        }
        __syncthreads();

        floatx4 s[4];
#pragma unroll
        for (int ki = 0; ki < 4; ++ki) {
            const bf16x8 kf0 = *(const bf16x8*)(Ks + (16 * ki + l15) * LDP + quad * 8);
            const bf16x8 kf1 = *(const bf16x8*)(Ks + (16 * ki + l15) * LDP + 32 + quad * 8);
            floatx4 c = {};
            c = __builtin_amdgcn_mfma_f32_16x16x32_bf16(qf0, kf0, c, 0, 0, 0);
            c = __builtin_amdgcn_mfma_f32_16x16x32_bf16(qf1, kf1, c, 0, 0, 0);
            s[ki] = c * SC2;
        }
        if (kt == qt) {
#pragma unroll
            for (int ki = 0; ki < 4; ++ki)
#pragma unroll
                for (int r = 0; r < 4; ++r)
                    if (16 * ki + l15 > 16 * w + quad * 4 + r) s[ki][r] = -INFINITY;
        }
#pragma unroll
        for (int ki = 0; ki < 4; ++ki)
#pragma unroll
            for (int r = 0; r < 4; ++r) {
                const float p = exp2f(s[ki][r]);
                s[ki][r] = p; lacc[r] += p;
            }

        unsigned short* Pw = Ps[w];
#pragma unroll
        for (int ki = 0; ki < 4; ++ki)
#pragma unroll
            for (int r = 0; r < 4; ++r)
                Pw[(quad * 4 + r) * LDP + 16 * ki + l15] = f2bf(s[ki][r]);

        const bf16x8 pf0 = *(const bf16x8*)(Pw + l15 * LDP + quad * 8);
        const bf16x8 pf1 = *(const bf16x8*)(Pw + l15 * LDP + 32 + quad * 8);
#pragma unroll
        for (int di = 0; di < 4; ++di) {
            const bf16x8 vf0 = *(const bf16x8*)(VTs + (16 * di + l15) * LDP + quad * 8);
            const bf16x8 vf1 = *(const bf16x8*)(VTs + (16 * di + l15) * LDP + 32 + quad * 8);
            O[di] = __builtin_amdgcn_mfma_f32_16x16x32_bf16(pf0, vf0, O[di], 0, 0, 0);
            O[di] = __builtin_amdgcn_mfma_f32_16x16x32_bf16(pf1, vf1, O[di], 0, 0, 0);
        }
    }
    float l_r[4];
#pragma unroll
    for (int r = 0; r < 4; ++r) {
        float v = lacc[r];
#pragma unroll
        for (int msk = 8; msk >= 1; msk >>= 1) v += __shfl_xor(v, msk, 64);
        l_r[r] = v;
    }
    float* outp = out + ((size_t)b * TT + q0 + 16 * w) * HH;
#pragma unroll
    for (int di = 0; di < 4; ++di)
#pragma unroll
        for (int r = 0; r < 4; ++r)
            outp[(quad * 4 + r) * HH + 16 * di + l15] = O[di][r] / l_r[r];
}

extern "C" void kernel_launch(void* const* d_in, const int* in_sizes, int n_in,
                              void* d_out, int out_size, void* d_ws, size_t ws_size,
                              hipStream_t stream) {
    const float* x  = (const float*)d_in[0];
    const float* Wq = (const float*)d_in[1];
    const float* Wk = (const float*)d_in[2];
    const float* Wv = (const float*)d_in[3];
    float* out = (float*)d_out;

    const size_t nQKV = (size_t)BB * TT * HH;           // 1 Mi elems
    unsigned short* qb  = (unsigned short*)d_ws;
    unsigned short* kb  = qb + nQKV;
    unsigned short* vbt = kb + nQKV;
    unsigned short* wtf = vbt + nQKV;                   // NN*CC ushorts
    unsigned short* Opart = wtf + (size_t)NN * CC;      // bf16 partials

    // CH=8: 32 q-tiles x NG=8 chunks x 128 rows; CH=16: NG=4
    const size_t prows8  = (size_t)BB * 32 * 8 * 128;
    const size_t prows16 = (size_t)BB * 32 * 4 * 128;
    float* lsum8  = (float*)(Opart + prows8 * HH);
    float* lsum16 = (float*)(Opart + prows16 * HH);
    const size_t need8  = (size_t)((char*)(lsum8  + prows8)  - (char*)d_ws);
    const size_t need16 = (size_t)((char*)(lsum16 + prows16) - (char*)d_ws);

    wprep<<<(NN * CC + 255) / 256, 256, 0, stream>>>(Wq, Wk, Wv, wtf);
    qkv_gemm<<<(BB * TT) / GR, 256, 0, stream>>>(x, wtf, qb, kb, vbt);
    if (ws_size >= need8) {
        attn_part<8><<<BB * 144, 256, 0, stream>>>(qb, kb, vbt, Opart, lsum8, out);
        attn_merge<8><<<(BB * TT * 8) / 256, 256, 0, stream>>>(Opart, lsum8, out);
    } else if (ws_size >= need16) {
        attn_part<16><<<BB * 80, 256, 0, stream>>>(qb, kb, vbt, Opart, lsum16, out);
        attn_merge<16><<<(BB * TT * 8) / 256, 256, 0, stream>>>(Opart, lsum16, out);
    } else {
        attn_full<<<BB * (TT / 64), 256, 0, stream>>>(qb, kb, vbt, out);
    }
}